// Round 7
// baseline (276.850 us; speedup 1.0000x reference)
//
#include <hip/hip_runtime.h>
#include <hip/hip_fp16.h>

#define NHEAD 8
#define NQ 300
#define NBS 32
#define VTOT 8500
#define CDIM 256
#define TQ 16
#define NQT 19  // ceil(300/16)
#define NBLK (NBS * NHEAD * NQT)  // 4864 = 8 XCDs x 608

typedef unsigned int u32x4 __attribute__((ext_vector_type(4)));

// ================= K1: cvt (odd blocks) || GEMM+softmax+P-precompute (even blocks) =================
__global__ __launch_bounds__(256)
void pre_kernel(const float* __restrict__ query,
                const float* __restrict__ refp,
                const float* __restrict__ value,
                const float* __restrict__ W_off,
                const float* __restrict__ b_off,
                const float* __restrict__ W_attn,
                const float* __restrict__ b_attn,
                __half* __restrict__ vh,
                int4* __restrict__ Pid_g,
                float4* __restrict__ Pw_g) {
    __shared__ float Aq[TQ * 260];
    __shared__ float S[TQ * 49];
    __shared__ float Rp[TQ * 4];

    const int tid = threadIdx.x;

    if (blockIdx.x & 1) {
        // ---- cvt role: value fp32 -> fp16, grid-strided, nt stores ----
        const int n8 = NBS * VTOT * CDIM / 8;   // 8,704,000
        int idx = (blockIdx.x >> 1) * 256 + tid;
        const int stride = NBLK * 256;
        for (int i = idx; i < n8; i += stride) {
            const float4* p = reinterpret_cast<const float4*>(value) + (size_t)i * 2;
            float4 a = p[0], bv = p[1];
            __half2 pk[4];
            pk[0] = __halves2half2(__float2half(a.x),  __float2half(a.y));
            pk[1] = __halves2half2(__float2half(a.z),  __float2half(a.w));
            pk[2] = __halves2half2(__float2half(bv.x), __float2half(bv.y));
            pk[3] = __halves2half2(__float2half(bv.z), __float2half(bv.w));
            __builtin_nontemporal_store(*reinterpret_cast<u32x4*>(pk),
                                        reinterpret_cast<u32x4*>(vh + (size_t)i * 8));
        }
        return;
    }

    // ---- precompute role ----
    const int bid = blockIdx.x >> 1;        // logical 0..NBLK-1, b-major
    const int b   = bid / (NHEAD * NQT);
    const int r   = bid - b * (NHEAD * NQT);
    const int h   = r / NQT;
    const int qt  = r - h * NQT;
    const int q0  = qt * TQ;

    // phase 0: stage query tile + reference points
    #pragma unroll
    for (int i = 0; i < 4; ++i) {
        int f4 = i * 256 + tid;
        int q  = f4 >> 6;
        int kk = (f4 & 63) << 2;
        float4 v = make_float4(0.f, 0.f, 0.f, 0.f);
        if (q0 + q < NQ)
            v = *reinterpret_cast<const float4*>(
                    query + ((size_t)(b * NQ + q0 + q) * CDIM + kk));
        *reinterpret_cast<float4*>(&Aq[q * 260 + kk]) = v;
    }
    if (tid < TQ * 4) {
        int q = tid >> 2, c = tid & 3;
        Rp[tid] = (q0 + q < NQ) ? refp[((size_t)(b * NQ + q0 + q)) * 4 + c] : 0.5f;
    }
    __syncthreads();

    // phase 1: GEMM 16q x 48 outputs, thread = (q, 4-col group)
    if (tid < 192) {
        const int q = tid / 12;
        const int g = tid - q * 12;
        const float* Wp;
        const float* bp;
        int stride, colbase, j;
        if (g < 8) {
            Wp = W_off;  bp = b_off;  stride = 256;
            colbase = h * 32 + 4 * g;  j = 4 * g;
        } else {
            Wp = W_attn; bp = b_attn; stride = 128;
            colbase = h * 16 + 4 * (g - 8); j = 32 + 4 * (g - 8);
        }
        float4 acc = *reinterpret_cast<const float4*>(bp + colbase);
        const float* a    = &Aq[q * 260];
        const float* wrow = Wp + colbase;
        #pragma unroll 2
        for (int k = 0; k < CDIM; k += 4) {
            float4 av = *reinterpret_cast<const float4*>(a + k);
            float4 w0 = *reinterpret_cast<const float4*>(wrow + (size_t)(k + 0) * stride);
            float4 w1 = *reinterpret_cast<const float4*>(wrow + (size_t)(k + 1) * stride);
            float4 w2 = *reinterpret_cast<const float4*>(wrow + (size_t)(k + 2) * stride);
            float4 w3 = *reinterpret_cast<const float4*>(wrow + (size_t)(k + 3) * stride);
            acc.x = fmaf(av.x, w0.x, acc.x); acc.y = fmaf(av.x, w0.y, acc.y);
            acc.z = fmaf(av.x, w0.z, acc.z); acc.w = fmaf(av.x, w0.w, acc.w);
            acc.x = fmaf(av.y, w1.x, acc.x); acc.y = fmaf(av.y, w1.y, acc.y);
            acc.z = fmaf(av.y, w1.z, acc.z); acc.w = fmaf(av.y, w1.w, acc.w);
            acc.x = fmaf(av.z, w2.x, acc.x); acc.y = fmaf(av.z, w2.y, acc.y);
            acc.z = fmaf(av.z, w2.z, acc.z); acc.w = fmaf(av.z, w2.w, acc.w);
            acc.x = fmaf(av.w, w3.x, acc.x); acc.y = fmaf(av.w, w3.y, acc.y);
            acc.z = fmaf(av.w, w3.z, acc.z); acc.w = fmaf(av.w, w3.w, acc.w);
        }
        S[q * 49 + j + 0] = acc.x;
        S[q * 49 + j + 1] = acc.y;
        S[q * 49 + j + 2] = acc.z;
        S[q * 49 + j + 3] = acc.w;
    }
    __syncthreads();

    // phase 2: softmax + location + corner idx / premultiplied weights -> ws
    {
        const int q = tid >> 4;
        const int p = tid & 15;
        const float* Sq = &S[q * 49];

        float m = Sq[32];
        #pragma unroll
        for (int jj = 1; jj < 16; ++jj) m = fmaxf(m, Sq[32 + jj]);
        float ssum = 0.f;
        #pragma unroll
        for (int jj = 0; jj < 16; ++jj) ssum += __expf(Sq[32 + jj] - m);
        float aw = __expf(Sq[32 + p] - m) / ssum;

        float offx = Sq[2 * p], offy = Sq[2 * p + 1];
        float rx = Rp[q * 4 + 0], ry = Rp[q * 4 + 1];
        float rw = Rp[q * 4 + 2], rh = Rp[q * 4 + 3];
        float locx = rx + offx * 0.25f * rw * 0.5f;
        float locy = ry + offy * 0.25f * rh * 0.5f;

        int l  = p >> 2;
        int Wl = 80 >> l;
        int Hl = Wl;
        int base = (l > 0 ? 6400 : 0) + (l > 1 ? 1600 : 0) + (l > 2 ? 400 : 0);

        float x = locx * (float)Wl - 0.5f;
        float y = locy * (float)Hl - 0.5f;
        float x0f = floorf(x), y0f = floorf(y);
        float lx = x - x0f, ly = y - y0f;
        int x0 = (int)x0f, y0 = (int)y0f;
        int x1 = x0 + 1,   y1 = y0 + 1;

        bool vx0 = (x0 >= 0) && (x0 < Wl);
        bool vx1 = (x1 >= 0) && (x1 < Wl);
        bool vy0 = (y0 >= 0) && (y0 < Hl);
        bool vy1 = (y1 >= 0) && (y1 < Hl);
        int cx0 = min(max(x0, 0), Wl - 1), cx1 = min(max(x1, 0), Wl - 1);
        int cy0 = min(max(y0, 0), Hl - 1), cy1 = min(max(y1, 0), Hl - 1);

        float wx0 = 1.f - lx, wy0 = 1.f - ly;
        float w00 = wx0 * wy0 * aw * (float)(vx0 && vy0);
        float w10 = lx  * wy0 * aw * (float)(vx1 && vy0);
        float w01 = wx0 * ly  * aw * (float)(vx0 && vy1);
        float w11 = lx  * ly  * aw * (float)(vx1 && vy1);

        int s = (p + q) & 15;  // bank swizzle (matched by gather kernel)
        Pid_g[(size_t)bid * 256 + q * 16 + s] =
            make_int4(base + cy0 * Wl + cx0, base + cy0 * Wl + cx1,
                      base + cy1 * Wl + cx0, base + cy1 * Wl + cx1);
        Pw_g[(size_t)bid * 256 + q * 16 + s] = make_float4(w00, w10, w01, w11);
    }
}

// ================= K2: pure gather-accumulate =================
__global__ __launch_bounds__(256, 4)
void gather_kernel(const __half* __restrict__ vh,
                   const int4* __restrict__ Pid_g,
                   const float4* __restrict__ Pw_g,
                   float* __restrict__ out) {
    __shared__ int4   Lid[256];
    __shared__ float4 Lw[256];

    const int tid = threadIdx.x;
    // Chunked XCD swizzle: pid%8 = XCD -> contiguous b-major chunk per XCD.
    const int pid = blockIdx.x;
    const int bid = (pid & 7) * (NBLK / 8) + (pid >> 3);
    const int b   = bid / (NHEAD * NQT);
    const int r   = bid - b * (NHEAD * NQT);
    const int h   = r / NQT;
    const int qt  = r - h * NQT;
    const int q0  = qt * TQ;

    Lid[tid] = Pid_g[(size_t)bid * 256 + tid];
    Lw[tid]  = Pw_g[(size_t)bid * 256 + tid];
    __syncthreads();

    const int cp4 = tid & 3;          // 16B quad within the 64B segment
    const int ps  = (tid >> 2) & 3;   // 4-way p-split
    const int q   = tid >> 4;         // 16 q
    const ushort* vbase = reinterpret_cast<const ushort*>(vh)
                          + (size_t)b * VTOT * CDIM + h * 32 + cp4 * 8;

    // preload all 4 P entries to registers
    int4 id0, id1, id2, id3;
    float4 w0, w1, w2, w3;
    { int s = (ps + 0  + q) & 15; id0 = Lid[q * 16 + s]; w0 = Lw[q * 16 + s]; }
    { int s = (ps + 4  + q) & 15; id1 = Lid[q * 16 + s]; w1 = Lw[q * 16 + s]; }
    { int s = (ps + 8  + q) & 15; id2 = Lid[q * 16 + s]; w2 = Lw[q * 16 + s]; }
    { int s = (ps + 12 + q) & 15; id3 = Lid[q * 16 + s]; w3 = Lw[q * 16 + s]; }

    float a0 = 0.f, a1 = 0.f, a2 = 0.f, a3 = 0.f;
    float a4 = 0.f, a5 = 0.f, a6 = 0.f, a7 = 0.f;

    #define ACC8(dv, wv)                                                   \
    {                                                                      \
        float2 f0 = __half22float2(*reinterpret_cast<__half2*>(&dv.x));    \
        float2 f1 = __half22float2(*reinterpret_cast<__half2*>(&dv.y));    \
        float2 f2 = __half22float2(*reinterpret_cast<__half2*>(&dv.z));    \
        float2 f3 = __half22float2(*reinterpret_cast<__half2*>(&dv.w));    \
        a0 = fmaf(wv, f0.x, a0); a1 = fmaf(wv, f0.y, a1);                  \
        a2 = fmaf(wv, f1.x, a2); a3 = fmaf(wv, f1.y, a3);                  \
        a4 = fmaf(wv, f2.x, a4); a5 = fmaf(wv, f2.y, a5);                  \
        a6 = fmaf(wv, f3.x, a6); a7 = fmaf(wv, f3.y, a7);                  \
    }

    // half 1: 8 gathers in flight (id0, id1)
    {
        uint4 d0 = *reinterpret_cast<const uint4*>(vbase + (size_t)id0.x * CDIM);
        uint4 d1 = *reinterpret_cast<const uint4*>(vbase + (size_t)id0.y * CDIM);
        uint4 d2 = *reinterpret_cast<const uint4*>(vbase + (size_t)id0.z * CDIM);
        uint4 d3 = *reinterpret_cast<const uint4*>(vbase + (size_t)id0.w * CDIM);
        uint4 d4 = *reinterpret_cast<const uint4*>(vbase + (size_t)id1.x * CDIM);
        uint4 d5 = *reinterpret_cast<const uint4*>(vbase + (size_t)id1.y * CDIM);
        uint4 d6 = *reinterpret_cast<const uint4*>(vbase + (size_t)id1.z * CDIM);
        uint4 d7 = *reinterpret_cast<const uint4*>(vbase + (size_t)id1.w * CDIM);
        ACC8(d0, w0.x); ACC8(d1, w0.y); ACC8(d2, w0.z); ACC8(d3, w0.w);
        ACC8(d4, w1.x); ACC8(d5, w1.y); ACC8(d6, w1.z); ACC8(d7, w1.w);
    }
    // half 2: 8 gathers in flight (id2, id3)
    {
        uint4 d0 = *reinterpret_cast<const uint4*>(vbase + (size_t)id2.x * CDIM);
        uint4 d1 = *reinterpret_cast<const uint4*>(vbase + (size_t)id2.y * CDIM);
        uint4 d2 = *reinterpret_cast<const uint4*>(vbase + (size_t)id2.z * CDIM);
        uint4 d3 = *reinterpret_cast<const uint4*>(vbase + (size_t)id2.w * CDIM);
        uint4 d4 = *reinterpret_cast<const uint4*>(vbase + (size_t)id3.x * CDIM);
        uint4 d5 = *reinterpret_cast<const uint4*>(vbase + (size_t)id3.y * CDIM);
        uint4 d6 = *reinterpret_cast<const uint4*>(vbase + (size_t)id3.z * CDIM);
        uint4 d7 = *reinterpret_cast<const uint4*>(vbase + (size_t)id3.w * CDIM);
        ACC8(d0, w2.x); ACC8(d1, w2.y); ACC8(d2, w2.z); ACC8(d3, w2.w);
        ACC8(d4, w3.x); ACC8(d5, w3.y); ACC8(d6, w3.z); ACC8(d7, w3.w);
    }
    #undef ACC8

    // reduce over ps (lane bits 2,3)
    #pragma unroll
    for (int m = 4; m <= 8; m <<= 1) {
        a0 += __shfl_xor(a0, m, 64); a1 += __shfl_xor(a1, m, 64);
        a2 += __shfl_xor(a2, m, 64); a3 += __shfl_xor(a3, m, 64);
        a4 += __shfl_xor(a4, m, 64); a5 += __shfl_xor(a5, m, 64);
        a6 += __shfl_xor(a6, m, 64); a7 += __shfl_xor(a7, m, 64);
    }

    int qg = q0 + q;
    if (ps == 0 && qg < NQ) {
        float* op = out + ((size_t)(b * NQ + qg)) * CDIM + h * 32 + cp4 * 8;
        *reinterpret_cast<float4*>(op)     = make_float4(a0, a1, a2, a3);
        *reinterpret_cast<float4*>(op + 4) = make_float4(a4, a5, a6, a7);
    }
}

// ================= fp32 single-kernel fallback if ws too small =================
__global__ __launch_bounds__(256, 8)
void msda_kernel_f32(const float* __restrict__ query,
                     const float* __restrict__ refp,
                     const float* __restrict__ value,
                     const float* __restrict__ W_off,
                     const float* __restrict__ b_off,
                     const float* __restrict__ W_attn,
                     const float* __restrict__ b_attn,
                     float* __restrict__ out) {
    __shared__ float Aq[TQ * 260];
    __shared__ float S[TQ * 49];
    __shared__ float Rp[TQ * 4];
    float* P = Aq;

    const int tid = threadIdx.x;
    const int bh  = blockIdx.x & 255;
    const int b   = bh >> 3;
    const int h   = bh & 7;
    const int qt  = blockIdx.x >> 8;
    const int q0  = qt * TQ;

    #pragma unroll
    for (int i = 0; i < 4; ++i) {
        int f4 = i * 256 + tid;
        int q  = f4 >> 6;
        int kk = (f4 & 63) << 2;
        float4 v = make_float4(0.f, 0.f, 0.f, 0.f);
        if (q0 + q < NQ)
            v = *reinterpret_cast<const float4*>(
                    query + ((size_t)(b * NQ + q0 + q) * CDIM + kk));
        *reinterpret_cast<float4*>(&Aq[q * 260 + kk]) = v;
    }
    if (tid < TQ * 4) {
        int q = tid >> 2, c = tid & 3;
        Rp[tid] = (q0 + q < NQ) ? refp[((size_t)(b * NQ + q0 + q)) * 4 + c] : 0.5f;
    }
    __syncthreads();

    if (tid < 192) {
        const int q = tid / 12;
        const int g = tid - q * 12;
        const float* Wp; const float* bp;
        int stride, colbase, j;
        if (g < 8) { Wp = W_off;  bp = b_off;  stride = 256; colbase = h * 32 + 4 * g; j = 4 * g; }
        else       { Wp = W_attn; bp = b_attn; stride = 128; colbase = h * 16 + 4 * (g - 8); j = 32 + 4 * (g - 8); }
        float4 acc = *reinterpret_cast<const float4*>(bp + colbase);
        const float* a    = &Aq[q * 260];
        const float* wrow = Wp + colbase;
        for (int k = 0; k < CDIM; k += 4) {
            float4 av = *reinterpret_cast<const float4*>(a + k);
            float4 w0 = *reinterpret_cast<const float4*>(wrow + (size_t)(k + 0) * stride);
            float4 w1 = *reinterpret_cast<const float4*>(wrow + (size_t)(k + 1) * stride);
            float4 w2 = *reinterpret_cast<const float4*>(wrow + (size_t)(k + 2) * stride);
            float4 w3 = *reinterpret_cast<const float4*>(wrow + (size_t)(k + 3) * stride);
            acc.x = fmaf(av.x, w0.x, acc.x); acc.y = fmaf(av.x, w0.y, acc.y);
            acc.z = fmaf(av.x, w0.z, acc.z); acc.w = fmaf(av.x, w0.w, acc.w);
            acc.x = fmaf(av.y, w1.x, acc.x); acc.y = fmaf(av.y, w1.y, acc.y);
            acc.z = fmaf(av.y, w1.z, acc.z); acc.w = fmaf(av.y, w1.w, acc.w);
            acc.x = fmaf(av.z, w2.x, acc.x); acc.y = fmaf(av.z, w2.y, acc.y);
            acc.z = fmaf(av.z, w2.z, acc.z); acc.w = fmaf(av.z, w2.w, acc.w);
            acc.x = fmaf(av.w, w3.x, acc.x); acc.y = fmaf(av.w, w3.y, acc.y);
            acc.z = fmaf(av.w, w3.z, acc.z); acc.w = fmaf(av.w, w3.w, acc.w);
        }
        S[q * 49 + j + 0] = acc.x; S[q * 49 + j + 1] = acc.y;
        S[q * 49 + j + 2] = acc.z; S[q * 49 + j + 3] = acc.w;
    }
    __syncthreads();

    {
        const int q = tid >> 4;
        const int p = tid & 15;
        const float* Sq = &S[q * 49];
        float m = Sq[32];
        #pragma unroll
        for (int jj = 1; jj < 16; ++jj) m = fmaxf(m, Sq[32 + jj]);
        float ssum = 0.f;
        #pragma unroll
        for (int jj = 0; jj < 16; ++jj) ssum += __expf(Sq[32 + jj] - m);
        float aw = __expf(Sq[32 + p] - m) / ssum;

        float offx = Sq[2 * p], offy = Sq[2 * p + 1];
        float rx = Rp[q * 4 + 0], ry = Rp[q * 4 + 1];
        float rw = Rp[q * 4 + 2], rh = Rp[q * 4 + 3];
        float locx = rx + offx * 0.25f * rw * 0.5f;
        float locy = ry + offy * 0.25f * rh * 0.5f;

        int l  = p >> 2;
        int Wl = 80 >> l, Hl = Wl;
        int base = (l > 0 ? 6400 : 0) + (l > 1 ? 1600 : 0) + (l > 2 ? 400 : 0);
        float x = locx * (float)Wl - 0.5f;
        float y = locy * (float)Hl - 0.5f;
        float x0f = floorf(x), y0f = floorf(y);
        float lx = x - x0f, ly = y - y0f;
        int x0 = (int)x0f, y0 = (int)y0f;
        int x1 = x0 + 1,   y1 = y0 + 1;
        bool vx0 = (x0 >= 0) && (x0 < Wl);
        bool vx1 = (x1 >= 0) && (x1 < Wl);
        bool vy0 = (y0 >= 0) && (y0 < Hl);
        bool vy1 = (y1 >= 0) && (y1 < Hl);
        int cx0 = min(max(x0, 0), Wl - 1), cx1 = min(max(x1, 0), Wl - 1);
        int cy0 = min(max(y0, 0), Hl - 1), cy1 = min(max(y1, 0), Hl - 1);
        float wx0 = 1.f - lx, wy0 = 1.f - ly;
        float w00 = wx0 * wy0 * aw * (float)(vx0 && vy0);
        float w10 = lx  * wy0 * aw * (float)(vx1 && vy0);
        float w01 = wx0 * ly  * aw * (float)(vx0 && vy1);
        float w11 = lx  * ly  * aw * (float)(vx1 && vy1);

        float* Pe = &P[(q * 16 + p) * 8];
        Pe[0] = __int_as_float(base + cy0 * Wl + cx0);
        Pe[1] = __int_as_float(base + cy0 * Wl + cx1);
        Pe[2] = __int_as_float(base + cy1 * Wl + cx0);
        Pe[3] = __int_as_float(base + cy1 * Wl + cx1);
        Pe[4] = w00; Pe[5] = w10; Pe[6] = w01; Pe[7] = w11;
    }
    __syncthreads();

    {
        const int qi = tid >> 5;
        const int ch = tid & 31;
        const float* vptr = value + (size_t)b * VTOT * CDIM + h * 32 + ch;
        for (int qq = qi; qq < TQ; qq += 8) {
            float acc = 0.f;
            #pragma unroll
            for (int p = 0; p < 16; ++p) {
                const float* Pe = &P[(qq * 16 + p) * 8];
                int4   id = *reinterpret_cast<const int4*>(Pe);
                float4 w  = *reinterpret_cast<const float4*>(Pe + 4);
                acc = fmaf(w.x, vptr[(size_t)id.x * CDIM], acc);
                acc = fmaf(w.y, vptr[(size_t)id.y * CDIM], acc);
                acc = fmaf(w.z, vptr[(size_t)id.z * CDIM], acc);
                acc = fmaf(w.w, vptr[(size_t)id.w * CDIM], acc);
            }
            int q = q0 + qq;
            if (q < NQ)
                out[((size_t)b * NQ + q) * CDIM + h * 32 + ch] = acc;
        }
    }
}

extern "C" void kernel_launch(void* const* d_in, const int* in_sizes, int n_in,
                              void* d_out, int out_size, void* d_ws, size_t ws_size,
                              hipStream_t stream) {
    const float* query  = (const float*)d_in[0];
    const float* refp   = (const float*)d_in[1];
    const float* value  = (const float*)d_in[2];
    const float* W_off  = (const float*)d_in[3];
    const float* b_off  = (const float*)d_in[4];
    const float* W_attn = (const float*)d_in[5];
    const float* b_attn = (const float*)d_in[6];
    float* out = (float*)d_out;

    const size_t vh_bytes = (size_t)NBS * VTOT * CDIM * sizeof(__half);  // 139,264,000
    const size_t p_bytes  = (size_t)NBLK * 256 * 16;                     // 19,922,944
    const size_t need = vh_bytes + 2 * p_bytes;                          // ~179 MB

    if (ws_size >= need) {
        __half* vh   = (__half*)d_ws;
        int4*   Pid  = (int4*)((char*)d_ws + vh_bytes);
        float4* Pw   = (float4*)((char*)d_ws + vh_bytes + p_bytes);
        pre_kernel<<<2 * NBLK, 256, 0, stream>>>(query, refp, value, W_off, b_off,
                                                 W_attn, b_attn, vh, Pid, Pw);
        gather_kernel<<<NBLK, 256, 0, stream>>>(vh, Pid, Pw, out);
    } else {
        msda_kernel_f32<<<NQT * 256, 256, 0, stream>>>(query, refp, value, W_off, b_off,
                                                       W_attn, b_attn, out);
    }
}

// Round 8
// 238.574 us; speedup vs baseline: 1.1604x; 1.1604x over previous
//
#include <hip/hip_runtime.h>
#include <hip/hip_fp16.h>

#define NHEAD 8
#define NQ 300
#define NBS 32
#define VTOT 8500
#define CDIM 256
#define TQ 16
#define NQT 19  // ceil(300/16)
#define NBLK (NBS * NHEAD * NQT)  // 4864 = 8 XCDs x 608

typedef unsigned int u32x4 __attribute__((ext_vector_type(4)));

// ================= K1: value fp32 -> fp16 (nt stores) =================
__global__ __launch_bounds__(256)
void cvt_kernel(const float* __restrict__ in, __half* __restrict__ o, int n8) {
    int idx = blockIdx.x * 256 + threadIdx.x;
    int stride = gridDim.x * 256;
    for (int i = idx; i < n8; i += stride) {
        const float4* p = reinterpret_cast<const float4*>(in) + (size_t)i * 2;
        float4 a = p[0], bv = p[1];
        __half2 pk[4];
        pk[0] = __halves2half2(__float2half(a.x),  __float2half(a.y));
        pk[1] = __halves2half2(__float2half(a.z),  __float2half(a.w));
        pk[2] = __halves2half2(__float2half(bv.x), __float2half(bv.y));
        pk[3] = __halves2half2(__float2half(bv.z), __float2half(bv.w));
        __builtin_nontemporal_store(*reinterpret_cast<u32x4*>(pk),
                                    reinterpret_cast<u32x4*>(o + (size_t)i * 8));
    }
}

// ================= K2: GEMM + softmax + P-table precompute =================
__global__ __launch_bounds__(256)
void pre_kernel(const float* __restrict__ query,
                const float* __restrict__ refp,
                const float* __restrict__ W_off,
                const float* __restrict__ b_off,
                const float* __restrict__ W_attn,
                const float* __restrict__ b_attn,
                int4* __restrict__ Pid_g,
                float4* __restrict__ Pw_g) {
    __shared__ float Aq[TQ * 260];
    __shared__ float S[TQ * 49];
    __shared__ float Rp[TQ * 4];

    const int tid = threadIdx.x;
    const int bid = blockIdx.x;             // b-major
    const int b   = bid / (NHEAD * NQT);
    const int r   = bid - b * (NHEAD * NQT);
    const int h   = r / NQT;
    const int qt  = r - h * NQT;
    const int q0  = qt * TQ;

    // phase 0: stage query tile + reference points
    #pragma unroll
    for (int i = 0; i < 4; ++i) {
        int f4 = i * 256 + tid;
        int q  = f4 >> 6;
        int kk = (f4 & 63) << 2;
        float4 v = make_float4(0.f, 0.f, 0.f, 0.f);
        if (q0 + q < NQ)
            v = *reinterpret_cast<const float4*>(
                    query + ((size_t)(b * NQ + q0 + q) * CDIM + kk));
        *reinterpret_cast<float4*>(&Aq[q * 260 + kk]) = v;
    }
    if (tid < TQ * 4) {
        int q = tid >> 2, c = tid & 3;
        Rp[tid] = (q0 + q < NQ) ? refp[((size_t)(b * NQ + q0 + q)) * 4 + c] : 0.5f;
    }
    __syncthreads();

    // phase 1: GEMM 16q x 48 outputs, thread = (q, 4-col group)
    if (tid < 192) {
        const int q = tid / 12;
        const int g = tid - q * 12;
        const float* Wp;
        const float* bp;
        int stride, colbase, j;
        if (g < 8) {
            Wp = W_off;  bp = b_off;  stride = 256;
            colbase = h * 32 + 4 * g;  j = 4 * g;
        } else {
            Wp = W_attn; bp = b_attn; stride = 128;
            colbase = h * 16 + 4 * (g - 8); j = 32 + 4 * (g - 8);
        }
        float4 acc = *reinterpret_cast<const float4*>(bp + colbase);
        const float* a    = &Aq[q * 260];
        const float* wrow = Wp + colbase;
        #pragma unroll 2
        for (int k = 0; k < CDIM; k += 4) {
            float4 av = *reinterpret_cast<const float4*>(a + k);
            float4 w0 = *reinterpret_cast<const float4*>(wrow + (size_t)(k + 0) * stride);
            float4 w1 = *reinterpret_cast<const float4*>(wrow + (size_t)(k + 1) * stride);
            float4 w2 = *reinterpret_cast<const float4*>(wrow + (size_t)(k + 2) * stride);
            float4 w3 = *reinterpret_cast<const float4*>(wrow + (size_t)(k + 3) * stride);
            acc.x = fmaf(av.x, w0.x, acc.x); acc.y = fmaf(av.x, w0.y, acc.y);
            acc.z = fmaf(av.x, w0.z, acc.z); acc.w = fmaf(av.x, w0.w, acc.w);
            acc.x = fmaf(av.y, w1.x, acc.x); acc.y = fmaf(av.y, w1.y, acc.y);
            acc.z = fmaf(av.y, w1.z, acc.z); acc.w = fmaf(av.y, w1.w, acc.w);
            acc.x = fmaf(av.z, w2.x, acc.x); acc.y = fmaf(av.z, w2.y, acc.y);
            acc.z = fmaf(av.z, w2.z, acc.z); acc.w = fmaf(av.z, w2.w, acc.w);
            acc.x = fmaf(av.w, w3.x, acc.x); acc.y = fmaf(av.w, w3.y, acc.y);
            acc.z = fmaf(av.w, w3.z, acc.z); acc.w = fmaf(av.w, w3.w, acc.w);
        }
        S[q * 49 + j + 0] = acc.x;
        S[q * 49 + j + 1] = acc.y;
        S[q * 49 + j + 2] = acc.z;
        S[q * 49 + j + 3] = acc.w;
    }
    __syncthreads();

    // phase 2: softmax + location + corner idx / premultiplied weights -> ws
    {
        const int q = tid >> 4;
        const int p = tid & 15;
        const float* Sq = &S[q * 49];

        float m = Sq[32];
        #pragma unroll
        for (int jj = 1; jj < 16; ++jj) m = fmaxf(m, Sq[32 + jj]);
        float ssum = 0.f;
        #pragma unroll
        for (int jj = 0; jj < 16; ++jj) ssum += __expf(Sq[32 + jj] - m);
        float aw = __expf(Sq[32 + p] - m) / ssum;

        float offx = Sq[2 * p], offy = Sq[2 * p + 1];
        float rx = Rp[q * 4 + 0], ry = Rp[q * 4 + 1];
        float rw = Rp[q * 4 + 2], rh = Rp[q * 4 + 3];
        float locx = rx + offx * 0.25f * rw * 0.5f;
        float locy = ry + offy * 0.25f * rh * 0.5f;

        int l  = p >> 2;
        int Wl = 80 >> l;
        int Hl = Wl;
        int base = (l > 0 ? 6400 : 0) + (l > 1 ? 1600 : 0) + (l > 2 ? 400 : 0);

        float x = locx * (float)Wl - 0.5f;
        float y = locy * (float)Hl - 0.5f;
        float x0f = floorf(x), y0f = floorf(y);
        float lx = x - x0f, ly = y - y0f;
        int x0 = (int)x0f, y0 = (int)y0f;
        int x1 = x0 + 1,   y1 = y0 + 1;

        bool vx0 = (x0 >= 0) && (x0 < Wl);
        bool vx1 = (x1 >= 0) && (x1 < Wl);
        bool vy0 = (y0 >= 0) && (y0 < Hl);
        bool vy1 = (y1 >= 0) && (y1 < Hl);
        int cx0 = min(max(x0, 0), Wl - 1), cx1 = min(max(x1, 0), Wl - 1);
        int cy0 = min(max(y0, 0), Hl - 1), cy1 = min(max(y1, 0), Hl - 1);

        float wx0 = 1.f - lx, wy0 = 1.f - ly;
        float w00 = wx0 * wy0 * aw * (float)(vx0 && vy0);
        float w10 = lx  * wy0 * aw * (float)(vx1 && vy0);
        float w01 = wx0 * ly  * aw * (float)(vx0 && vy1);
        float w11 = lx  * ly  * aw * (float)(vx1 && vy1);

        int s = (p + q) & 15;  // swizzle (matched by gather kernel)
        Pid_g[(size_t)bid * 256 + q * 16 + s] =
            make_int4(base + cy0 * Wl + cx0, base + cy0 * Wl + cx1,
                      base + cy1 * Wl + cx0, base + cy1 * Wl + cx1);
        Pw_g[(size_t)bid * 256 + q * 16 + s] = make_float4(w00, w10, w01, w11);
    }
}

// ================= K3: pure gather-accumulate =================
__global__ __launch_bounds__(256, 4)
void gather_kernel(const __half* __restrict__ vh,
                   const int4* __restrict__ Pid_g,
                   const float4* __restrict__ Pw_g,
                   float* __restrict__ out) {
    __shared__ int4   Lid[256];
    __shared__ float4 Lw[256];

    const int tid = threadIdx.x;
    // Chunked XCD swizzle: pid%8 = XCD -> contiguous b-major chunk per XCD.
    const int pid = blockIdx.x;
    const int bid = (pid & 7) * (NBLK / 8) + (pid >> 3);
    const int b   = bid / (NHEAD * NQT);
    const int r   = bid - b * (NHEAD * NQT);
    const int h   = r / NQT;
    const int qt  = r - h * NQT;
    const int q0  = qt * TQ;

    Lid[tid] = Pid_g[(size_t)bid * 256 + tid];
    Lw[tid]  = Pw_g[(size_t)bid * 256 + tid];
    __syncthreads();

    const int cp4 = tid & 3;          // 16B quad within the 64B segment
    const int ps  = (tid >> 2) & 3;   // 4-way p-split
    const int q   = tid >> 4;         // 16 q
    const ushort* vbase = reinterpret_cast<const ushort*>(vh)
                          + (size_t)b * VTOT * CDIM + h * 32 + cp4 * 8;

    int4 id0, id1, id2, id3;
    float4 w0, w1, w2, w3;
    { int s = (ps + 0  + q) & 15; id0 = Lid[q * 16 + s]; w0 = Lw[q * 16 + s]; }
    { int s = (ps + 4  + q) & 15; id1 = Lid[q * 16 + s]; w1 = Lw[q * 16 + s]; }
    { int s = (ps + 8  + q) & 15; id2 = Lid[q * 16 + s]; w2 = Lw[q * 16 + s]; }
    { int s = (ps + 12 + q) & 15; id3 = Lid[q * 16 + s]; w3 = Lw[q * 16 + s]; }

    float a0 = 0.f, a1 = 0.f, a2 = 0.f, a3 = 0.f;
    float a4 = 0.f, a5 = 0.f, a6 = 0.f, a7 = 0.f;

    #define ACC8(dv, wv)                                                   \
    {                                                                      \
        float2 f0 = __half22float2(*reinterpret_cast<__half2*>(&dv.x));    \
        float2 f1 = __half22float2(*reinterpret_cast<__half2*>(&dv.y));    \
        float2 f2 = __half22float2(*reinterpret_cast<__half2*>(&dv.z));    \
        float2 f3 = __half22float2(*reinterpret_cast<__half2*>(&dv.w));    \
        a0 = fmaf(wv, f0.x, a0); a1 = fmaf(wv, f0.y, a1);                  \
        a2 = fmaf(wv, f1.x, a2); a3 = fmaf(wv, f1.y, a3);                  \
        a4 = fmaf(wv, f2.x, a4); a5 = fmaf(wv, f2.y, a5);                  \
        a6 = fmaf(wv, f3.x, a6); a7 = fmaf(wv, f3.y, a7);                  \
    }

    {
        uint4 d0 = *reinterpret_cast<const uint4*>(vbase + (size_t)id0.x * CDIM);
        uint4 d1 = *reinterpret_cast<const uint4*>(vbase + (size_t)id0.y * CDIM);
        uint4 d2 = *reinterpret_cast<const uint4*>(vbase + (size_t)id0.z * CDIM);
        uint4 d3 = *reinterpret_cast<const uint4*>(vbase + (size_t)id0.w * CDIM);
        uint4 d4 = *reinterpret_cast<const uint4*>(vbase + (size_t)id1.x * CDIM);
        uint4 d5 = *reinterpret_cast<const uint4*>(vbase + (size_t)id1.y * CDIM);
        uint4 d6 = *reinterpret_cast<const uint4*>(vbase + (size_t)id1.z * CDIM);
        uint4 d7 = *reinterpret_cast<const uint4*>(vbase + (size_t)id1.w * CDIM);
        ACC8(d0, w0.x); ACC8(d1, w0.y); ACC8(d2, w0.z); ACC8(d3, w0.w);
        ACC8(d4, w1.x); ACC8(d5, w1.y); ACC8(d6, w1.z); ACC8(d7, w1.w);
    }
    {
        uint4 d0 = *reinterpret_cast<const uint4*>(vbase + (size_t)id2.x * CDIM);
        uint4 d1 = *reinterpret_cast<const uint4*>(vbase + (size_t)id2.y * CDIM);
        uint4 d2 = *reinterpret_cast<const uint4*>(vbase + (size_t)id2.z * CDIM);
        uint4 d3 = *reinterpret_cast<const uint4*>(vbase + (size_t)id2.w * CDIM);
        uint4 d4 = *reinterpret_cast<const uint4*>(vbase + (size_t)id3.x * CDIM);
        uint4 d5 = *reinterpret_cast<const uint4*>(vbase + (size_t)id3.y * CDIM);
        uint4 d6 = *reinterpret_cast<const uint4*>(vbase + (size_t)id3.z * CDIM);
        uint4 d7 = *reinterpret_cast<const uint4*>(vbase + (size_t)id3.w * CDIM);
        ACC8(d0, w2.x); ACC8(d1, w2.y); ACC8(d2, w2.z); ACC8(d3, w2.w);
        ACC8(d4, w3.x); ACC8(d5, w3.y); ACC8(d6, w3.z); ACC8(d7, w3.w);
    }
    #undef ACC8

    #pragma unroll
    for (int m = 4; m <= 8; m <<= 1) {
        a0 += __shfl_xor(a0, m, 64); a1 += __shfl_xor(a1, m, 64);
        a2 += __shfl_xor(a2, m, 64); a3 += __shfl_xor(a3, m, 64);
        a4 += __shfl_xor(a4, m, 64); a5 += __shfl_xor(a5, m, 64);
        a6 += __shfl_xor(a6, m, 64); a7 += __shfl_xor(a7, m, 64);
    }

    int qg = q0 + q;
    if (ps == 0 && qg < NQ) {
        float* op = out + ((size_t)(b * NQ + qg)) * CDIM + h * 32 + cp4 * 8;
        *reinterpret_cast<float4*>(op)     = make_float4(a0, a1, a2, a3);
        *reinterpret_cast<float4*>(op + 4) = make_float4(a4, a5, a6, a7);
    }
}

// ================= fp32 single-kernel fallback if ws too small =================
__global__ __launch_bounds__(256, 8)
void msda_kernel_f32(const float* __restrict__ query,
                     const float* __restrict__ refp,
                     const float* __restrict__ value,
                     const float* __restrict__ W_off,
                     const float* __restrict__ b_off,
                     const float* __restrict__ W_attn,
                     const float* __restrict__ b_attn,
                     float* __restrict__ out) {
    __shared__ float Aq[TQ * 260];
    __shared__ float S[TQ * 49];
    __shared__ float Rp[TQ * 4];
    float* P = Aq;

    const int tid = threadIdx.x;
    const int bh  = blockIdx.x & 255;
    const int b   = bh >> 3;
    const int h   = bh & 7;
    const int qt  = blockIdx.x >> 8;
    const int q0  = qt * TQ;

    #pragma unroll
    for (int i = 0; i < 4; ++i) {
        int f4 = i * 256 + tid;
        int q  = f4 >> 6;
        int kk = (f4 & 63) << 2;
        float4 v = make_float4(0.f, 0.f, 0.f, 0.f);
        if (q0 + q < NQ)
            v = *reinterpret_cast<const float4*>(
                    query + ((size_t)(b * NQ + q0 + q) * CDIM + kk));
        *reinterpret_cast<float4*>(&Aq[q * 260 + kk]) = v;
    }
    if (tid < TQ * 4) {
        int q = tid >> 2, c = tid & 3;
        Rp[tid] = (q0 + q < NQ) ? refp[((size_t)(b * NQ + q0 + q)) * 4 + c] : 0.5f;
    }
    __syncthreads();

    if (tid < 192) {
        const int q = tid / 12;
        const int g = tid - q * 12;
        const float* Wp; const float* bp;
        int stride, colbase, j;
        if (g < 8) { Wp = W_off;  bp = b_off;  stride = 256; colbase = h * 32 + 4 * g; j = 4 * g; }
        else       { Wp = W_attn; bp = b_attn; stride = 128; colbase = h * 16 + 4 * (g - 8); j = 32 + 4 * (g - 8); }
        float4 acc = *reinterpret_cast<const float4*>(bp + colbase);
        const float* a    = &Aq[q * 260];
        const float* wrow = Wp + colbase;
        for (int k = 0; k < CDIM; k += 4) {
            float4 av = *reinterpret_cast<const float4*>(a + k);
            float4 w0 = *reinterpret_cast<const float4*>(wrow + (size_t)(k + 0) * stride);
            float4 w1 = *reinterpret_cast<const float4*>(wrow + (size_t)(k + 1) * stride);
            float4 w2 = *reinterpret_cast<const float4*>(wrow + (size_t)(k + 2) * stride);
            float4 w3 = *reinterpret_cast<const float4*>(wrow + (size_t)(k + 3) * stride);
            acc.x = fmaf(av.x, w0.x, acc.x); acc.y = fmaf(av.x, w0.y, acc.y);
            acc.z = fmaf(av.x, w0.z, acc.z); acc.w = fmaf(av.x, w0.w, acc.w);
            acc.x = fmaf(av.y, w1.x, acc.x); acc.y = fmaf(av.y, w1.y, acc.y);
            acc.z = fmaf(av.y, w1.z, acc.z); acc.w = fmaf(av.y, w1.w, acc.w);
            acc.x = fmaf(av.z, w2.x, acc.x); acc.y = fmaf(av.z, w2.y, acc.y);
            acc.z = fmaf(av.z, w2.z, acc.z); acc.w = fmaf(av.z, w2.w, acc.w);
            acc.x = fmaf(av.w, w3.x, acc.x); acc.y = fmaf(av.w, w3.y, acc.y);
            acc.z = fmaf(av.w, w3.z, acc.z); acc.w = fmaf(av.w, w3.w, acc.w);
        }
        S[q * 49 + j + 0] = acc.x; S[q * 49 + j + 1] = acc.y;
        S[q * 49 + j + 2] = acc.z; S[q * 49 + j + 3] = acc.w;
    }
    __syncthreads();

    {
        const int q = tid >> 4;
        const int p = tid & 15;
        const float* Sq = &S[q * 49];
        float m = Sq[32];
        #pragma unroll
        for (int jj = 1; jj < 16; ++jj) m = fmaxf(m, Sq[32 + jj]);
        float ssum = 0.f;
        #pragma unroll
        for (int jj = 0; jj < 16; ++jj) ssum += __expf(Sq[32 + jj] - m);
        float aw = __expf(Sq[32 + p] - m) / ssum;

        float offx = Sq[2 * p], offy = Sq[2 * p + 1];
        float rx = Rp[q * 4 + 0], ry = Rp[q * 4 + 1];
        float rw = Rp[q * 4 + 2], rh = Rp[q * 4 + 3];
        float locx = rx + offx * 0.25f * rw * 0.5f;
        float locy = ry + offy * 0.25f * rh * 0.5f;

        int l  = p >> 2;
        int Wl = 80 >> l, Hl = Wl;
        int base = (l > 0 ? 6400 : 0) + (l > 1 ? 1600 : 0) + (l > 2 ? 400 : 0);
        float x = locx * (float)Wl - 0.5f;
        float y = locy * (float)Hl - 0.5f;
        float x0f = floorf(x), y0f = floorf(y);
        float lx = x - x0f, ly = y - y0f;
        int x0 = (int)x0f, y0 = (int)y0f;
        int x1 = x0 + 1,   y1 = y0 + 1;
        bool vx0 = (x0 >= 0) && (x0 < Wl);
        bool vx1 = (x1 >= 0) && (x1 < Wl);
        bool vy0 = (y0 >= 0) && (y0 < Hl);
        bool vy1 = (y1 >= 0) && (y1 < Hl);
        int cx0 = min(max(x0, 0), Wl - 1), cx1 = min(max(x1, 0), Wl - 1);
        int cy0 = min(max(y0, 0), Hl - 1), cy1 = min(max(y1, 0), Hl - 1);
        float wx0 = 1.f - lx, wy0 = 1.f - ly;
        float w00 = wx0 * wy0 * aw * (float)(vx0 && vy0);
        float w10 = lx  * wy0 * aw * (float)(vx1 && vy0);
        float w01 = wx0 * ly  * aw * (float)(vx0 && vy1);
        float w11 = lx  * ly  * aw * (float)(vx1 && vy1);

        float* Pe = &P[(q * 16 + p) * 8];
        Pe[0] = __int_as_float(base + cy0 * Wl + cx0);
        Pe[1] = __int_as_float(base + cy0 * Wl + cx1);
        Pe[2] = __int_as_float(base + cy1 * Wl + cx0);
        Pe[3] = __int_as_float(base + cy1 * Wl + cx1);
        Pe[4] = w00; Pe[5] = w10; Pe[6] = w01; Pe[7] = w11;
    }
    __syncthreads();

    {
        const int qi = tid >> 5;
        const int ch = tid & 31;
        const float* vptr = value + (size_t)b * VTOT * CDIM + h * 32 + ch;
        for (int qq = qi; qq < TQ; qq += 8) {
            float acc = 0.f;
            #pragma unroll
            for (int p = 0; p < 16; ++p) {
                const float* Pe = &P[(qq * 16 + p) * 8];
                int4   id = *reinterpret_cast<const int4*>(Pe);
                float4 w  = *reinterpret_cast<const float4*>(Pe + 4);
                acc = fmaf(w.x, vptr[(size_t)id.x * CDIM], acc);
                acc = fmaf(w.y, vptr[(size_t)id.y * CDIM], acc);
                acc = fmaf(w.z, vptr[(size_t)id.z * CDIM], acc);
                acc = fmaf(w.w, vptr[(size_t)id.w * CDIM], acc);
            }
            int q = q0 + qq;
            if (q < NQ)
                out[((size_t)b * NQ + q) * CDIM + h * 32 + ch] = acc;
        }
    }
}

extern "C" void kernel_launch(void* const* d_in, const int* in_sizes, int n_in,
                              void* d_out, int out_size, void* d_ws, size_t ws_size,
                              hipStream_t stream) {
    const float* query  = (const float*)d_in[0];
    const float* refp   = (const float*)d_in[1];
    const float* value  = (const float*)d_in[2];
    const float* W_off  = (const float*)d_in[3];
    const float* b_off  = (const float*)d_in[4];
    const float* W_attn = (const float*)d_in[5];
    const float* b_attn = (const float*)d_in[6];
    float* out = (float*)d_out;

    const size_t vh_bytes = (size_t)NBS * VTOT * CDIM * sizeof(__half);  // 139,264,000
    const size_t p_bytes  = (size_t)NBLK * 256 * 16;                     // 19,922,944
    const size_t need = vh_bytes + 2 * p_bytes;                          // ~179 MB

    if (ws_size >= need) {
        __half* vh   = (__half*)d_ws;
        int4*   Pid  = (int4*)((char*)d_ws + vh_bytes);
        float4* Pw   = (float4*)((char*)d_ws + vh_bytes + p_bytes);
        cvt_kernel<<<2048, 256, 0, stream>>>(value, vh, NBS * VTOT * CDIM / 8);
        pre_kernel<<<NBLK, 256, 0, stream>>>(query, refp, W_off, b_off,
                                             W_attn, b_attn, Pid, Pw);
        gather_kernel<<<NBLK, 256, 0, stream>>>(vh, Pid, Pw, out);
    } else {
        msda_kernel_f32<<<NQT * 256, 256, 0, stream>>>(query, refp, value, W_off, b_off,
                                                       W_attn, b_attn, out);
    }
}

// Round 9
// 209.834 us; speedup vs baseline: 1.3194x; 1.1370x over previous
//
#include <hip/hip_runtime.h>
#include <hip/hip_fp16.h>

#define NHEAD 8
#define NQ 300
#define NBS 32
#define VTOT 8500
#define CDIM 256
#define TQ 16
#define NQT 19  // ceil(300/16)
#define NBLK (NBS * NHEAD * NQT)  // 4864 = 8 XCDs x 608

typedef unsigned int u32x4 __attribute__((ext_vector_type(4)));

// ======= K1: value fp32 [b][idx][256] -> fp16 head-major [(b*8+h)*VTOT+idx][32] =======
__global__ __launch_bounds__(256)
void cvt_kernel(const float* __restrict__ in, __half* __restrict__ o) {
    const int TOT = NBS * VTOT * 32;      // 8-channel tasks
    int gid = blockIdx.x * 256 + threadIdx.x;
    int stride = gridDim.x * 256;
    for (int t = gid; t < TOT; t += stride) {
        int pt = t >> 5;                  // global point: b*VTOT + idx
        int u  = t & 31;                  // head = u>>2, chan-quad = u&3
        int b  = pt / VTOT;
        int idx = pt - b * VTOT;
        int h  = u >> 2;
        int cq = u & 3;
        const float* src = in + (size_t)pt * CDIM + h * 32 + cq * 8;
        float4 f0 = *reinterpret_cast<const float4*>(src);
        float4 f1 = *reinterpret_cast<const float4*>(src + 4);
        __half2 pk[4];
        pk[0] = __halves2half2(__float2half(f0.x), __float2half(f0.y));
        pk[1] = __halves2half2(__float2half(f0.z), __float2half(f0.w));
        pk[2] = __halves2half2(__float2half(f1.x), __float2half(f1.y));
        pk[3] = __halves2half2(__float2half(f1.z), __float2half(f1.w));
        __half* dst = o + ((size_t)(b * NHEAD + h) * VTOT + idx) * 32 + cq * 8;
        __builtin_nontemporal_store(*reinterpret_cast<u32x4*>(pk),
                                    reinterpret_cast<u32x4*>(dst));
    }
}

// ======= K2: fused GEMM + softmax + paired-corner gather (head-major fp16) =======
__global__ __launch_bounds__(256, 4)
void msda_kernel_f16(const float* __restrict__ query,
                     const float* __restrict__ refp,
                     const __half* __restrict__ vh,
                     const float* __restrict__ W_off,
                     const float* __restrict__ b_off,
                     const float* __restrict__ W_attn,
                     const float* __restrict__ b_attn,
                     float* __restrict__ out) {
    __shared__ float Aq[TQ * 260];        // aliased by Pid2/Pw after phase 1
    __shared__ float S[TQ * 49];
    __shared__ float Rp[TQ * 4];

    int2*   Pid2 = reinterpret_cast<int2*>(Aq);           // 256 int2  = 2048 B
    float4* Pw   = reinterpret_cast<float4*>(Aq + 512);   // 256 float4 = 4096 B

    const int tid = threadIdx.x;
    // Chunked XCD swizzle: pid%8 = XCD -> contiguous b-major chunk per XCD.
    const int pid = blockIdx.x;
    const int bid = (pid & 7) * (NBLK / 8) + (pid >> 3);
    const int b   = bid / (NHEAD * NQT);
    const int r_  = bid - b * (NHEAD * NQT);
    const int h   = r_ / NQT;
    const int qt  = r_ - h * NQT;
    const int q0  = qt * TQ;

    // ---- phase 0: stage query tile + reference points ----
    #pragma unroll
    for (int i = 0; i < 4; ++i) {
        int f4 = i * 256 + tid;
        int q  = f4 >> 6;
        int kk = (f4 & 63) << 2;
        float4 v = make_float4(0.f, 0.f, 0.f, 0.f);
        if (q0 + q < NQ)
            v = *reinterpret_cast<const float4*>(
                    query + ((size_t)(b * NQ + q0 + q) * CDIM + kk));
        *reinterpret_cast<float4*>(&Aq[q * 260 + kk]) = v;
    }
    if (tid < TQ * 4) {
        int q = tid >> 2, c = tid & 3;
        Rp[tid] = (q0 + q < NQ) ? refp[((size_t)(b * NQ + q0 + q)) * 4 + c] : 0.5f;
    }
    __syncthreads();

    // ---- phase 1: GEMM 16q x 48 outputs, thread = (q, 4-col group) ----
    if (tid < 192) {
        const int q = tid / 12;
        const int g = tid - q * 12;
        const float* Wp;
        const float* bp;
        int stride, colbase, j;
        if (g < 8) {
            Wp = W_off;  bp = b_off;  stride = 256;
            colbase = h * 32 + 4 * g;  j = 4 * g;
        } else {
            Wp = W_attn; bp = b_attn; stride = 128;
            colbase = h * 16 + 4 * (g - 8); j = 32 + 4 * (g - 8);
        }
        float4 acc = *reinterpret_cast<const float4*>(bp + colbase);
        const float* a    = &Aq[q * 260];
        const float* wrow = Wp + colbase;
        #pragma unroll 2
        for (int k = 0; k < CDIM; k += 4) {
            float4 av = *reinterpret_cast<const float4*>(a + k);
            float4 w0 = *reinterpret_cast<const float4*>(wrow + (size_t)(k + 0) * stride);
            float4 w1 = *reinterpret_cast<const float4*>(wrow + (size_t)(k + 1) * stride);
            float4 w2 = *reinterpret_cast<const float4*>(wrow + (size_t)(k + 2) * stride);
            float4 w3 = *reinterpret_cast<const float4*>(wrow + (size_t)(k + 3) * stride);
            acc.x = fmaf(av.x, w0.x, acc.x); acc.y = fmaf(av.x, w0.y, acc.y);
            acc.z = fmaf(av.x, w0.z, acc.z); acc.w = fmaf(av.x, w0.w, acc.w);
            acc.x = fmaf(av.y, w1.x, acc.x); acc.y = fmaf(av.y, w1.y, acc.y);
            acc.z = fmaf(av.y, w1.z, acc.z); acc.w = fmaf(av.y, w1.w, acc.w);
            acc.x = fmaf(av.z, w2.x, acc.x); acc.y = fmaf(av.z, w2.y, acc.y);
            acc.z = fmaf(av.z, w2.z, acc.z); acc.w = fmaf(av.z, w2.w, acc.w);
            acc.x = fmaf(av.w, w3.x, acc.x); acc.y = fmaf(av.w, w3.y, acc.y);
            acc.z = fmaf(av.w, w3.z, acc.z); acc.w = fmaf(av.w, w3.w, acc.w);
        }
        S[q * 49 + j + 0] = acc.x;
        S[q * 49 + j + 1] = acc.y;
        S[q * 49 + j + 2] = acc.z;
        S[q * 49 + j + 3] = acc.w;
    }
    __syncthreads();

    // ---- phase 2: softmax + location + row-pair indices / slot weights ----
    {
        const int q = tid >> 4;
        const int p = tid & 15;
        const float* Sq = &S[q * 49];

        float m = Sq[32];
        #pragma unroll
        for (int jj = 1; jj < 16; ++jj) m = fmaxf(m, Sq[32 + jj]);
        float ssum = 0.f;
        #pragma unroll
        for (int jj = 0; jj < 16; ++jj) ssum += __expf(Sq[32 + jj] - m);
        float aw = __expf(Sq[32 + p] - m) / ssum;

        float offx = Sq[2 * p], offy = Sq[2 * p + 1];
        float rx = Rp[q * 4 + 0], ry = Rp[q * 4 + 1];
        float rw = Rp[q * 4 + 2], rh = Rp[q * 4 + 3];
        float locx = rx + offx * 0.25f * rw * 0.5f;
        float locy = ry + offy * 0.25f * rh * 0.5f;

        int l  = p >> 2;
        int Wl = 80 >> l;
        int Hl = Wl;
        int base = (l > 0 ? 6400 : 0) + (l > 1 ? 1600 : 0) + (l > 2 ? 400 : 0);

        float x = locx * (float)Wl - 0.5f;
        float y = locy * (float)Hl - 0.5f;
        float x0f = floorf(x), y0f = floorf(y);
        float lx = x - x0f, ly = y - y0f;
        int x0 = (int)x0f, y0 = (int)y0f;
        int x1 = x0 + 1,   y1 = y0 + 1;

        bool vx0 = (x0 >= 0) && (x0 < Wl);
        bool vx1 = (x1 >= 0) && (x1 < Wl);
        bool vy0 = (y0 >= 0) && (y0 < Hl);
        bool vy1 = (y1 >= 0) && (y1 < Hl);
        int cx0 = min(max(x0, 0), Wl - 1), cx1 = min(max(x1, 0), Wl - 1);
        int cy0 = min(max(y0, 0), Hl - 1), cy1 = min(max(y1, 0), Hl - 1);

        float wx0 = 1.f - lx, wy0 = 1.f - ly;
        float w00 = wx0 * wy0 * aw * (float)(vx0 && vy0);
        float w10 = lx  * wy0 * aw * (float)(vx1 && vy0);
        float w01 = wx0 * ly  * aw * (float)(vx0 && vy1);
        float w11 = lx  * ly  * aw * (float)(vx1 && vy1);

        // fold x-corners into a contiguous pair [bx, bx+1] with slot weights
        int bx = min(max(x0, 0), Wl - 2);
        float ws00 = (cx0 == bx     ? w00 : 0.f) + (cx1 == bx     ? w10 : 0.f);
        float ws01 = (cx0 == bx + 1 ? w00 : 0.f) + (cx1 == bx + 1 ? w10 : 0.f);
        float ws10 = (cx0 == bx     ? w01 : 0.f) + (cx1 == bx     ? w11 : 0.f);
        float ws11 = (cx0 == bx + 1 ? w01 : 0.f) + (cx1 == bx + 1 ? w11 : 0.f);

        int s = (p + q) & 15;  // swizzle (matched by phase 3)
        Pid2[q * 16 + s] = make_int2(base + cy0 * Wl + bx, base + cy1 * Wl + bx);
        Pw[q * 16 + s]   = make_float4(ws00, ws01, ws10, ws11);
    }
    __syncthreads();

    // ---- phase 3: paired-corner gather. thread = (q, row r, 16B slot s8) ----
    {
        const int q  = tid >> 4;          // 16 q
        const int u  = tid & 15;
        const int r  = u >> 3;            // row select (y0 / y1)
        const int s8 = u & 7;             // 16B slot within the 128B x-pair
        const ushort* vbase = reinterpret_cast<const ushort*>(vh)
                              + (size_t)(b * NHEAD + h) * VTOT * 32 + s8 * 8;

        float a0 = 0.f, a1 = 0.f, a2 = 0.f, a3 = 0.f;
        float a4 = 0.f, a5 = 0.f, a6 = 0.f, a7 = 0.f;

        #pragma unroll
        for (int p = 0; p < 16; ++p) {
            int sw = (p + q) & 15;
            int2   rr = Pid2[q * 16 + sw];
            float4 wv = Pw[q * 16 + sw];
            int   rbase = r ? rr.y : rr.x;
            float w     = r ? (s8 < 4 ? wv.z : wv.w)
                            : (s8 < 4 ? wv.x : wv.y);
            uint4 d = *reinterpret_cast<const uint4*>(vbase + (size_t)rbase * 32);
            float2 f0 = __half22float2(*reinterpret_cast<__half2*>(&d.x));
            float2 f1 = __half22float2(*reinterpret_cast<__half2*>(&d.y));
            float2 f2 = __half22float2(*reinterpret_cast<__half2*>(&d.z));
            float2 f3 = __half22float2(*reinterpret_cast<__half2*>(&d.w));
            a0 = fmaf(w, f0.x, a0); a1 = fmaf(w, f0.y, a1);
            a2 = fmaf(w, f1.x, a2); a3 = fmaf(w, f1.y, a3);
            a4 = fmaf(w, f2.x, a4); a5 = fmaf(w, f2.y, a5);
            a6 = fmaf(w, f3.x, a6); a7 = fmaf(w, f3.y, a7);
        }

        // reduce over slot (lane bit 2) and row (lane bit 3)
        #pragma unroll
        for (int m = 4; m <= 8; m <<= 1) {
            a0 += __shfl_xor(a0, m, 64); a1 += __shfl_xor(a1, m, 64);
            a2 += __shfl_xor(a2, m, 64); a3 += __shfl_xor(a3, m, 64);
            a4 += __shfl_xor(a4, m, 64); a5 += __shfl_xor(a5, m, 64);
            a6 += __shfl_xor(a6, m, 64); a7 += __shfl_xor(a7, m, 64);
        }

        int qg = q0 + q;
        if (u < 4 && qg < NQ) {           // u == chan-quad
            float* op = out + ((size_t)(b * NQ + qg)) * CDIM + h * 32 + u * 8;
            *reinterpret_cast<float4*>(op)     = make_float4(a0, a1, a2, a3);
            *reinterpret_cast<float4*>(op + 4) = make_float4(a4, a5, a6, a7);
        }
    }
}

// ======= fp32 single-kernel fallback if ws too small =======
__global__ __launch_bounds__(256, 8)
void msda_kernel_f32(const float* __restrict__ query,
                     const float* __restrict__ refp,
                     const float* __restrict__ value,
                     const float* __restrict__ W_off,
                     const float* __restrict__ b_off,
                     const float* __restrict__ W_attn,
                     const float* __restrict__ b_attn,
                     float* __restrict__ out) {
    __shared__ float Aq[TQ * 260];
    __shared__ float S[TQ * 49];
    __shared__ float Rp[TQ * 4];
    float* P = Aq;

    const int tid = threadIdx.x;
    const int bh  = blockIdx.x & 255;
    const int b   = bh >> 3;
    const int h   = bh & 7;
    const int qt  = blockIdx.x >> 8;
    const int q0  = qt * TQ;

    #pragma unroll
    for (int i = 0; i < 4; ++i) {
        int f4 = i * 256 + tid;
        int q  = f4 >> 6;
        int kk = (f4 & 63) << 2;
        float4 v = make_float4(0.f, 0.f, 0.f, 0.f);
        if (q0 + q < NQ)
            v = *reinterpret_cast<const float4*>(
                    query + ((size_t)(b * NQ + q0 + q) * CDIM + kk));
        *reinterpret_cast<float4*>(&Aq[q * 260 + kk]) = v;
    }
    if (tid < TQ * 4) {
        int q = tid >> 2, c = tid & 3;
        Rp[tid] = (q0 + q < NQ) ? refp[((size_t)(b * NQ + q0 + q)) * 4 + c] : 0.5f;
    }
    __syncthreads();

    if (tid < 192) {
        const int q = tid / 12;
        const int g = tid - q * 12;
        const float* Wp; const float* bp;
        int stride, colbase, j;
        if (g < 8) { Wp = W_off;  bp = b_off;  stride = 256; colbase = h * 32 + 4 * g; j = 4 * g; }
        else       { Wp = W_attn; bp = b_attn; stride = 128; colbase = h * 16 + 4 * (g - 8); j = 32 + 4 * (g - 8); }
        float4 acc = *reinterpret_cast<const float4*>(bp + colbase);
        const float* a    = &Aq[q * 260];
        const float* wrow = Wp + colbase;
        for (int k = 0; k < CDIM; k += 4) {
            float4 av = *reinterpret_cast<const float4*>(a + k);
            float4 w0 = *reinterpret_cast<const float4*>(wrow + (size_t)(k + 0) * stride);
            float4 w1 = *reinterpret_cast<const float4*>(wrow + (size_t)(k + 1) * stride);
            float4 w2 = *reinterpret_cast<const float4*>(wrow + (size_t)(k + 2) * stride);
            float4 w3 = *reinterpret_cast<const float4*>(wrow + (size_t)(k + 3) * stride);
            acc.x = fmaf(av.x, w0.x, acc.x); acc.y = fmaf(av.x, w0.y, acc.y);
            acc.z = fmaf(av.x, w0.z, acc.z); acc.w = fmaf(av.x, w0.w, acc.w);
            acc.x = fmaf(av.y, w1.x, acc.x); acc.y = fmaf(av.y, w1.y, acc.y);
            acc.z = fmaf(av.y, w1.z, acc.z); acc.w = fmaf(av.y, w1.w, acc.w);
            acc.x = fmaf(av.z, w2.x, acc.x); acc.y = fmaf(av.z, w2.y, acc.y);
            acc.z = fmaf(av.z, w2.z, acc.z); acc.w = fmaf(av.z, w2.w, acc.w);
            acc.x = fmaf(av.w, w3.x, acc.x); acc.y = fmaf(av.w, w3.y, acc.y);
            acc.z = fmaf(av.w, w3.z, acc.z); acc.w = fmaf(av.w, w3.w, acc.w);
        }
        S[q * 49 + j + 0] = acc.x; S[q * 49 + j + 1] = acc.y;
        S[q * 49 + j + 2] = acc.z; S[q * 49 + j + 3] = acc.w;
    }
    __syncthreads();

    {
        const int q = tid >> 4;
        const int p = tid & 15;
        const float* Sq = &S[q * 49];
        float m = Sq[32];
        #pragma unroll
        for (int jj = 1; jj < 16; ++jj) m = fmaxf(m, Sq[32 + jj]);
        float ssum = 0.f;
        #pragma unroll
        for (int jj = 0; jj < 16; ++jj) ssum += __expf(Sq[32 + jj] - m);
        float aw = __expf(Sq[32 + p] - m) / ssum;

        float offx = Sq[2 * p], offy = Sq[2 * p + 1];
        float rx = Rp[q * 4 + 0], ry = Rp[q * 4 + 1];
        float rw = Rp[q * 4 + 2], rh = Rp[q * 4 + 3];
        float locx = rx + offx * 0.25f * rw * 0.5f;
        float locy = ry + offy * 0.25f * rh * 0.5f;

        int l  = p >> 2;
        int Wl = 80 >> l, Hl = Wl;
        int base = (l > 0 ? 6400 : 0) + (l > 1 ? 1600 : 0) + (l > 2 ? 400 : 0);
        float x = locx * (float)Wl - 0.5f;
        float y = locy * (float)Hl - 0.5f;
        float x0f = floorf(x), y0f = floorf(y);
        float lx = x - x0f, ly = y - y0f;
        int x0 = (int)x0f, y0 = (int)y0f;
        int x1 = x0 + 1,   y1 = y0 + 1;
        bool vx0 = (x0 >= 0) && (x0 < Wl);
        bool vx1 = (x1 >= 0) && (x1 < Wl);
        bool vy0 = (y0 >= 0) && (y0 < Hl);
        bool vy1 = (y1 >= 0) && (y1 < Hl);
        int cx0 = min(max(x0, 0), Wl - 1), cx1 = min(max(x1, 0), Wl - 1);
        int cy0 = min(max(y0, 0), Hl - 1), cy1 = min(max(y1, 0), Hl - 1);
        float wx0 = 1.f - lx, wy0 = 1.f - ly;
        float w00 = wx0 * wy0 * aw * (float)(vx0 && vy0);
        float w10 = lx  * wy0 * aw * (float)(vx1 && vy0);
        float w01 = wx0 * ly  * aw * (float)(vx0 && vy1);
        float w11 = lx  * ly  * aw * (float)(vx1 && vy1);

        float* Pe = &P[(q * 16 + p) * 8];
        Pe[0] = __int_as_float(base + cy0 * Wl + cx0);
        Pe[1] = __int_as_float(base + cy0 * Wl + cx1);
        Pe[2] = __int_as_float(base + cy1 * Wl + cx0);
        Pe[3] = __int_as_float(base + cy1 * Wl + cx1);
        Pe[4] = w00; Pe[5] = w10; Pe[6] = w01; Pe[7] = w11;
    }
    __syncthreads();

    {
        const int qi = tid >> 5;
        const int ch = tid & 31;
        const float* vptr = value + (size_t)b * VTOT * CDIM + h * 32 + ch;
        for (int qq = qi; qq < TQ; qq += 8) {
            float acc = 0.f;
            #pragma unroll
            for (int p = 0; p < 16; ++p) {
                const float* Pe = &P[(qq * 16 + p) * 8];
                int4   id = *reinterpret_cast<const int4*>(Pe);
                float4 w  = *reinterpret_cast<const float4*>(Pe + 4);
                acc = fmaf(w.x, vptr[(size_t)id.x * CDIM], acc);
                acc = fmaf(w.y, vptr[(size_t)id.y * CDIM], acc);
                acc = fmaf(w.z, vptr[(size_t)id.z * CDIM], acc);
                acc = fmaf(w.w, vptr[(size_t)id.w * CDIM], acc);
            }
            int q = q0 + qq;
            if (q < NQ)
                out[((size_t)b * NQ + q) * CDIM + h * 32 + ch] = acc;
        }
    }
}

extern "C" void kernel_launch(void* const* d_in, const int* in_sizes, int n_in,
                              void* d_out, int out_size, void* d_ws, size_t ws_size,
                              hipStream_t stream) {
    const float* query  = (const float*)d_in[0];
    const float* refp   = (const float*)d_in[1];
    const float* value  = (const float*)d_in[2];
    const float* W_off  = (const float*)d_in[3];
    const float* b_off  = (const float*)d_in[4];
    const float* W_attn = (const float*)d_in[5];
    const float* b_attn = (const float*)d_in[6];
    float* out = (float*)d_out;

    const size_t need = (size_t)NBS * VTOT * CDIM * sizeof(__half);  // 139 MB
    if (ws_size >= need) {
        __half* vh = (__half*)d_ws;
        cvt_kernel<<<2048, 256, 0, stream>>>(value, vh);
        msda_kernel_f16<<<NBLK, 256, 0, stream>>>(query, refp, vh, W_off, b_off,
                                                  W_attn, b_attn, out);
    } else {
        msda_kernel_f32<<<NQT * 256, 256, 0, stream>>>(query, refp, value, W_off, b_off,
                                                       W_attn, b_attn, out);
    }
}